// Round 11
// baseline (1641.769 us; speedup 1.0000x reference)
//
#include <hip/hip_runtime.h>
#include <hip/hip_bf16.h>

#define B_ 4
#define L_ 4096
#define E_ 1024
#define H_ 16
#define D_ 64
#define MLP_ 4096
#define M_ (B_*L_)
#define LK_ (L_+1)

typedef short bf16x8 __attribute__((ext_vector_type(8)));
typedef float f32x4 __attribute__((ext_vector_type(4)));
typedef unsigned short u16;

__device__ __forceinline__ u16 f2bf(float f){
    union { float f; unsigned u; } x; x.f = f;
    unsigned r = x.u + 0x7FFFu + ((x.u >> 16) & 1u);
    return (u16)(r >> 16);
}
__device__ __forceinline__ float bf2f(u16 u){
    union { unsigned u; float f; } x; x.u = ((unsigned)u) << 16;
    return x.f;
}

__device__ __forceinline__ void gload16(const u16* g, const u16* l){
    __builtin_amdgcn_global_load_lds(
        (const __attribute__((address_space(1))) void*)g,
        (__attribute__((address_space(3))) void*)l, 16, 0, 0);
}

// ---------------- weight convert+transpose: in f32 [K,N] -> out bf16 [N,K] ----------------
__global__ __launch_bounds__(256)
void wcvt(const float* __restrict__ in, u16* __restrict__ out, int K, int N)
{
    __shared__ float t[32][33];
    int tid = threadIdx.x;
    int tx = tid & 31, ty = tid >> 5;      // 8 rows per iter
    int bk = blockIdx.y, bn = blockIdx.x;
    #pragma unroll
    for (int i=0;i<4;++i)
        t[ty+8*i][tx] = in[(size_t)(bk*32 + ty + 8*i)*N + bn*32 + tx];
    __syncthreads();
    #pragma unroll
    for (int i=0;i<4;++i)
        out[(size_t)(bn*32 + ty + 8*i)*K + bk*32 + tx] = f2bf(t[tx][ty+8*i]);
}

// ---------------- x convert f32 -> bf16 ----------------
__global__ __launch_bounds__(256)
void xcvt(const float* __restrict__ in, u16* __restrict__ out)
{
    size_t i = ((size_t)blockIdx.x*256 + threadIdx.x)*4;
    float4 v = *(const float4*)(in + i);
    ushort4 o; o.x=f2bf(v.x); o.y=f2bf(v.y); o.z=f2bf(v.z); o.w=f2bf(v.w);
    *(ushort4*)(out + i) = o;
}

// ---------------- bf16 MFMA GEMM: C = A[M,K] @ Wt[N,K]^T + bias ----------------
// Staging: global_load_lds 16B, linear LDS dest, PRE-SWIZZLED global source
// (content lands where the XOR-swizzled fragment reads expect it).
// EPI 0: bf16 out; 1: tanh+1 -> bf16; 2: (tanh+1)*alpha -> bf16 (P1=alpha, N=1024);
// EPI 3: gelu -> bf16; 4: f32 out = v + P1 + P2
template<int EPI>
__global__ __launch_bounds__(256)
void gemm_bf16(const u16* __restrict__ A, const u16* __restrict__ Wt,
               const float* __restrict__ bias, void* __restrict__ Cout,
               int M, int N, int K,
               const float* __restrict__ P1, const float* __restrict__ P2)
{
    __shared__ u16 As[128*64];
    __shared__ u16 Bs[128*64];
    const int tid = threadIdx.x;
    const int bm = blockIdx.y, bn = blockIdx.x;
    const int lane = tid & 63, w = tid >> 6;
    const int wr = w >> 1, wc = w & 1;
    const int row16 = lane & 15, kb = lane >> 4;
    const u16* Abase = A  + (size_t)bm*128*K;
    const u16* Bbase = Wt + (size_t)bn*128*K;
    f32x4 acc[4][4] = {};

    for (int kt = 0; kt < K; kt += 64) {
        #pragma unroll
        for (int c4 = 0; c4 < 4; ++c4) {
            int seg  = c4*32 + w*8;                 // starting row of this wave's 1KB chunk
            int row  = seg + (lane >> 3);
            int col8 = (lane & 7) ^ (row & 7);      // inverse-swizzled source block
            gload16(Abase + (size_t)row*K + kt + col8*8, As + seg*64);
            gload16(Bbase + (size_t)row*K + kt + col8*8, Bs + seg*64);
        }
        __syncthreads();                            // drains vmcnt before barrier
        #pragma unroll
        for (int kk = 0; kk < 2; ++kk) {
            bf16x8 af[4], bfr[4];
            #pragma unroll
            for (int mi = 0; mi < 4; ++mi) {
                int r = wr*64 + mi*16 + row16;
                int off = r*128 + ((kk*64 + kb*16) ^ ((row16 & 7) << 4));
                af[mi] = *(const bf16x8*)((const char*)As + off);
            }
            #pragma unroll
            for (int nj = 0; nj < 4; ++nj) {
                int r = wc*64 + nj*16 + row16;
                int off = r*128 + ((kk*64 + kb*16) ^ ((row16 & 7) << 4));
                bfr[nj] = *(const bf16x8*)((const char*)Bs + off);
            }
            #pragma unroll
            for (int mi = 0; mi < 4; ++mi)
                #pragma unroll
                for (int nj = 0; nj < 4; ++nj)
                    acc[mi][nj] = __builtin_amdgcn_mfma_f32_16x16x32_bf16(af[mi], bfr[nj], acc[mi][nj], 0, 0, 0);
        }
        __syncthreads();
    }
    #pragma unroll
    for (int nj = 0; nj < 4; ++nj) {
        int col = bn*128 + wc*64 + nj*16 + row16;
        float bcol = bias[col];
        #pragma unroll
        for (int mi = 0; mi < 4; ++mi) {
            int rbase = bm*128 + wr*64 + mi*16 + kb*4;
            #pragma unroll
            for (int r = 0; r < 4; ++r) {
                int row = rbase + r;
                float v = acc[mi][nj][r] + bcol;
                if (EPI == 1) v = tanhf(v) + 1.0f;
                if (EPI == 2) {
                    int b = row >> 12, l = row & 4095, h = col >> 6;
                    v = (tanhf(v) + 1.0f) * P1[(size_t)(b*16 + h)*LK_ + 1 + l];
                }
                if (EPI == 3) v = 0.5f*v*(1.0f + erff(v*0.70710678118654752f));
                if (EPI == 4) {
                    ((float*)Cout)[(size_t)row*N + col] = v + P1[(size_t)row*N + col] + P2[(size_t)row*N + col];
                } else {
                    ((u16*)Cout)[(size_t)row*N + col] = f2bf(v);
                }
            }
        }
    }
}

// ---------------- row LayerNorm over E=1024 (bf16 in-place) ----------------
__global__ __launch_bounds__(256)
void ln_bf16(u16* __restrict__ x, const float* __restrict__ g, const float* __restrict__ bta)
{
    __shared__ float red[8];
    const int row = blockIdx.x, tid = threadIdx.x;
    u16* p = x + (size_t)row*E_;
    ushort4 raw = *(const ushort4*)(p + tid*4);
    float v[4] = {bf2f(raw.x), bf2f(raw.y), bf2f(raw.z), bf2f(raw.w)};
    float s=0.f, s2=0.f;
    #pragma unroll
    for (int i=0;i<4;++i){ s += v[i]; s2 += v[i]*v[i]; }
    #pragma unroll
    for (int o=32;o;o>>=1){ s += __shfl_xor(s,o); s2 += __shfl_xor(s2,o); }
    int wv = tid >> 6;
    if ((tid & 63) == 0){ red[wv] = s; red[4+wv] = s2; }
    __syncthreads();
    s  = red[0]+red[1]+red[2]+red[3];
    s2 = red[4]+red[5]+red[6]+red[7];
    float mu = s * (1.0f/E_);
    float var = s2 * (1.0f/E_) - mu*mu;
    float rs = rsqrtf(var + 1e-5f);
    ushort4 o4;
    float r0 = (v[0]-mu)*rs*g[tid*4+0] + bta[tid*4+0];
    float r1 = (v[1]-mu)*rs*g[tid*4+1] + bta[tid*4+1];
    float r2 = (v[2]-mu)*rs*g[tid*4+2] + bta[tid*4+2];
    float r3 = (v[3]-mu)*rs*g[tid*4+3] + bta[tid*4+3];
    o4.x=f2bf(r0); o4.y=f2bf(r1); o4.z=f2bf(r2); o4.w=f2bf(r3);
    *(ushort4*)(p + tid*4) = o4;
}

// ---------------- final LN: bf16 in -> f32 out + bf16 out ----------------
__global__ __launch_bounds__(256)
void ln_dual(const u16* __restrict__ x, const float* __restrict__ g, const float* __restrict__ bta,
             float* __restrict__ of, u16* __restrict__ ob)
{
    __shared__ float red[8];
    const int row = blockIdx.x, tid = threadIdx.x;
    const u16* p = x + (size_t)row*E_;
    ushort4 raw = *(const ushort4*)(p + tid*4);
    float v[4] = {bf2f(raw.x), bf2f(raw.y), bf2f(raw.z), bf2f(raw.w)};
    float s=0.f, s2=0.f;
    #pragma unroll
    for (int i=0;i<4;++i){ s += v[i]; s2 += v[i]*v[i]; }
    #pragma unroll
    for (int o=32;o;o>>=1){ s += __shfl_xor(s,o); s2 += __shfl_xor(s2,o); }
    int wv = tid >> 6;
    if ((tid & 63) == 0){ red[wv] = s; red[4+wv] = s2; }
    __syncthreads();
    s  = red[0]+red[1]+red[2]+red[3];
    s2 = red[4]+red[5]+red[6]+red[7];
    float mu = s * (1.0f/E_);
    float var = s2 * (1.0f/E_) - mu*mu;
    float rs = rsqrtf(var + 1e-5f);
    float4 rf; ushort4 o4;
    rf.x = (v[0]-mu)*rs*g[tid*4+0] + bta[tid*4+0];
    rf.y = (v[1]-mu)*rs*g[tid*4+1] + bta[tid*4+1];
    rf.z = (v[2]-mu)*rs*g[tid*4+2] + bta[tid*4+2];
    rf.w = (v[3]-mu)*rs*g[tid*4+3] + bta[tid*4+3];
    o4.x=f2bf(rf.x); o4.y=f2bf(rf.y); o4.z=f2bf(rf.z); o4.w=f2bf(rf.w);
    *(float4*)(of + (size_t)row*E_ + tid*4) = rf;
    *(ushort4*)(ob + (size_t)row*E_ + tid*4) = o4;
}

// ---------------- qg partial sums (bf16 Q) ----------------
__global__ __launch_bounds__(1024)
void qg_partial(const u16* __restrict__ Q, float* __restrict__ qg)
{
    int b = blockIdx.x >> 6;
    int c = blockIdx.x & 63;
    int e = threadIdx.x;
    float s = 0.f;
    const u16* p = Q + ((size_t)b*L_ + c*64)*E_ + e;
    for (int l=0; l<64; ++l) s += bf2f(p[(size_t)l*E_]);
    atomicAdd(&qg[b*E_ + e], s);
}

// ---------------- RALA scores: scores[b,h,l] = dot(qs[b,h,:], K[b,l,h,:]) ----------------
__global__ __launch_bounds__(256)
void rala_scores(const u16* __restrict__ K, const float* __restrict__ qg,
                 float* __restrict__ scores)
{
    int blk = blockIdx.x;              // 0..M_/64-1
    int row0 = blk * 64;
    int b = row0 >> 12;
    int tid = threadIdx.x;
    int lane = tid & 63, w = tid >> 6;
    float qr[16];
    const float qscale = 1.0f/(L_ * 8.0f);     // mean over L, / sqrt(D)=8
    #pragma unroll
    for (int j=0;j<16;++j) qr[j] = qg[b*E_ + lane*16 + j] * qscale;
    for (int it = 0; it < 16; ++it) {
        int r = row0 + w*16 + it;
        const u16* p = K + (size_t)r*E_ + lane*16;
        uint4 a0 = *(const uint4*)(p);
        uint4 a1 = *(const uint4*)(p + 8);
        const u16* u0 = (const u16*)&a0;
        const u16* u1 = (const u16*)&a1;
        float s = 0.f;
        #pragma unroll
        for (int j=0;j<8;++j) s = fmaf(bf2f(u0[j]), qr[j], s);
        #pragma unroll
        for (int j=0;j<8;++j) s = fmaf(bf2f(u1[j]), qr[8+j], s);
        s += __shfl_xor(s, 1);
        s += __shfl_xor(s, 2);
        if ((lane & 3) == 0) {
            int h = lane >> 2;
            int l = r & (L_-1);
            scores[((size_t)(b*H_ + h))*L_ + l] = s;
        }
    }
}

// ---------------- softmax over L+1 (zero token at 0) -> alpha ----------------
__global__ __launch_bounds__(256)
void rala_softmax(const float* __restrict__ scores, float* __restrict__ alpha)
{
    __shared__ float red[8];
    int bh = blockIdx.x, tid = threadIdx.x;
    const float* sc = scores + (size_t)bh*L_;
    float v[16];
    float mx = 0.f;                            // zero-token score = 0 included
    #pragma unroll
    for (int i=0;i<16;++i){ v[i] = sc[tid + i*256]; mx = fmaxf(mx, v[i]); }
    #pragma unroll
    for (int o=32;o;o>>=1) mx = fmaxf(mx, __shfl_xor(mx,o));
    int wv = tid >> 6;
    if ((tid & 63) == 0) red[wv] = mx;
    __syncthreads();
    mx = fmaxf(fmaxf(red[0],red[1]), fmaxf(red[2],red[3]));
    float sum = 0.f;
    #pragma unroll
    for (int i=0;i<16;++i){ v[i] = expf(v[i]-mx); sum += v[i]; }
    #pragma unroll
    for (int o=32;o;o>>=1) sum += __shfl_xor(sum,o);
    __syncthreads();
    if ((tid & 63) == 0) red[4+wv] = sum;
    __syncthreads();
    float Z = red[4]+red[5]+red[6]+red[7] + expf(-mx);
    float scale = (float)L_ / Z;
    float* al = alpha + (size_t)bh*LK_;
    #pragma unroll
    for (int i=0;i<16;++i) al[1 + tid + i*256] = v[i]*scale;
    if (tid==0) al[0] = expf(-mx)*scale;
}

// ---------------- KV[b,h,64,64] & Ksum[b,h,64] from scaled phiKs (bf16) & V (bf16) ----------------
#define NS_ 8
__global__ __launch_bounds__(256)
void kv_partial(const u16* __restrict__ phiKs, const u16* __restrict__ Vb,
                float* __restrict__ KV, float* __restrict__ Ksum)
{
    __shared__ float Ps[64][65];
    __shared__ float Vs[64][65];
    int blk = blockIdx.x;
    int s = blk & (NS_-1);
    int h = (blk >> 3) & 15;
    int b = blk >> 7;
    int tid = threadIdx.x;
    int tx = tid & 15, ty = tid >> 4;
    const size_t bh = (size_t)(b*H_ + h);
    float acc[4][4] = {};
    float ksl = 0.f;
    for (int ch = 0; ch < 8; ++ch) {
        int lbase = s*512 + ch*64;
        #pragma unroll
        for (int i=0;i<16;++i){
            int idx = tid + i*256;
            int r = idx >> 6, c2 = idx & 63;
            size_t g = ((size_t)b*L_ + lbase + r)*E_ + h*64 + c2;
            Ps[r][c2] = bf2f(phiKs[g]);
            Vs[r][c2] = bf2f(Vb[g]);
        }
        __syncthreads();
        #pragma unroll 8
        for (int l=0; l<64; ++l){
            float p[4], vv[4];
            #pragma unroll
            for (int i=0;i<4;++i) p[i] = Ps[l][ty*4+i];
            #pragma unroll
            for (int j=0;j<4;++j) vv[j] = Vs[l][tx*4+j];
            #pragma unroll
            for (int i=0;i<4;++i)
                #pragma unroll
                for (int j=0;j<4;++j)
                    acc[i][j] = fmaf(p[i], vv[j], acc[i][j]);
        }
        if (tid < 64){
            float t = 0.f;
            #pragma unroll 8
            for (int l=0; l<64; ++l) t += Ps[l][tid];
            ksl += t;
        }
        __syncthreads();
    }
    #pragma unroll
    for (int i=0;i<4;++i)
        #pragma unroll
        for (int j=0;j<4;++j)
            atomicAdd(&KV[(bh*D_ + ty*4+i)*D_ + tx*4+j], acc[i][j]);
    if (tid < 64) atomicAdd(&Ksum[bh*D_ + tid], ksl);
}

// zero-token: Ksum += (tanh(bphi_k)+1) * alpha0
__global__ void ksum_zero(const float* __restrict__ bphi_k,
                          const float* __restrict__ alpha, float* __restrict__ Ksum)
{
    int bh = blockIdx.x; int h = bh & 15; int d = threadIdx.x;
    float a0 = alpha[(size_t)bh*LK_];
    Ksum[(size_t)bh*D_ + d] += (tanhf(bphi_k[h*D_ + d]) + 1.0f) * a0;
}

// ---------------- attn = (phiQ @ KV) / (phiQ . Ksum + eps), bf16 out ----------------
__global__ __launch_bounds__(256)
void attn_core(const u16* __restrict__ phiQ, const float* __restrict__ KV,
               const float* __restrict__ Ksum, u16* __restrict__ attn)
{
    __shared__ float KVs[64][65];
    __shared__ float Ps[64][65];
    __shared__ float Ks_[64];
    int gid = blockIdx.x;
    int h = gid & 15; int rchunk = gid >> 4;
    int row0 = rchunk * 64;
    int b = row0 >> 12;
    const size_t bh = (size_t)(b*H_ + h);
    int tid = threadIdx.x;
    int tx = tid & 15, ty = tid >> 4;
    #pragma unroll
    for (int i=0;i<16;++i){
        int idx = tid + i*256;
        int r = idx >> 6, c2 = idx & 63;
        KVs[r][c2] = KV[bh*D_*D_ + r*64 + c2];
        Ps[r][c2]  = bf2f(phiQ[((size_t)row0 + r)*E_ + h*64 + c2]);
    }
    if (tid < 64) Ks_[tid] = Ksum[bh*D_ + tid];
    __syncthreads();
    float num[4][4] = {};
    float den[4] = {};
    for (int d=0; d<64; ++d){
        float kd = Ks_[d];
        float4 kv4 = *(const float4*)&KVs[d][tx*4];
        float kvv[4] = {kv4.x, kv4.y, kv4.z, kv4.w};
        #pragma unroll
        for (int i=0;i<4;++i){
            float q = Ps[ty*4+i][d];
            den[i] = fmaf(q, kd, den[i]);
            #pragma unroll
            for (int j=0;j<4;++j)
                num[i][j] = fmaf(q, kvv[j], num[i][j]);
        }
    }
    #pragma unroll
    for (int i=0;i<4;++i){
        float r = 1.0f / (den[i] + 1e-6f);
        #pragma unroll
        for (int j=0;j<4;++j)
            attn[((size_t)row0 + ty*4 + i)*E_ + h*64 + tx*4 + j] = f2bf(num[i][j] * r);
    }
}

// ---------------- grouped conv (k=5,pad=2,groups=H) + gated residual (bf16 io) ----------------
// lane = e column (64), wave = 16-row l-group; weights in registers, As_ reads broadcast.
__global__ __launch_bounds__(256)
void conv_residual(const u16* __restrict__ attn, const float* __restrict__ conv_w,
                   const float* __restrict__ conv_b, const float* __restrict__ gamma_p,
                   u16* __restrict__ out)
{
    __shared__ float As_[68][65];      // [l-2 .. l+65][d], pad 65
    int blk = blockIdx.x;
    int lc = blk & 63; int h = (blk>>6) & 15; int b = blk >> 10;
    int tid = threadIdx.x;
    int e = tid & 63;                  // e column within head
    int lg = tid >> 6;                 // wave = 16-row group
    for (int i=tid; i<68*64; i+=256){
        int r = i>>6, cc = i&63;
        int l = lc*64 - 2 + r;
        As_[r][cc] = (l>=0 && l<L_) ? bf2f(attn[((size_t)b*L_+l)*E_ + h*D_ + cc]) : 0.f;
    }
    __syncthreads();
    float acc[16] = {};
    const float* wbase = conv_w + ((size_t)(h*D_ + e))*320;   // w[e][d][t]
    for (int d=0; d<64; ++d){
        float w0 = wbase[d*5+0], w1 = wbase[d*5+1], w2 = wbase[d*5+2],
              w3 = wbase[d*5+3], w4 = wbase[d*5+4];
        float a[20];
        #pragma unroll
        for (int r=0;r<20;++r) a[r] = As_[lg*16 + r][d];      // wave-broadcast reads
        #pragma unroll
        for (int i=0;i<16;++i)
            acc[i] = fmaf(a[i+4],w4, fmaf(a[i+3],w3, fmaf(a[i+2],w2,
                     fmaf(a[i+1],w1, fmaf(a[i+0],w0, acc[i])))));
    }
    float gamma = *gamma_p;
    float bc = conv_b[h*D_ + e];
    #pragma unroll
    for (int i=0;i<16;++i){
        int l = lc*64 + lg*16 + i;
        float v = As_[lg*16 + i + 2][e] + gamma*(acc[i] + bc);
        out[((size_t)b*L_+l)*E_ + h*D_ + e] = f2bf(v);
    }
}

extern "C" void kernel_launch(void* const* d_in, const int* in_sizes, int n_in,
                              void* d_out, int out_size, void* d_ws, size_t ws_size,
                              hipStream_t stream)
{
    const float* x     = (const float*)d_in[0];
    const float* Wq    = (const float*)d_in[1];
    const float* bq    = (const float*)d_in[2];
    const float* lnq_g = (const float*)d_in[3];
    const float* lnq_b = (const float*)d_in[4];
    const float* Wk    = (const float*)d_in[5];
    const float* bk    = (const float*)d_in[6];
    const float* lnk_g = (const float*)d_in[7];
    const float* lnk_b = (const float*)d_in[8];
    const float* Wv    = (const float*)d_in[9];
    const float* bv    = (const float*)d_in[10];
    const float* lnv_g = (const float*)d_in[11];
    const float* lnv_b = (const float*)d_in[12];
    const float* Wphi_q= (const float*)d_in[13];
    const float* bphi_q= (const float*)d_in[14];
    const float* Wphi_k= (const float*)d_in[15];
    const float* bphi_k= (const float*)d_in[16];
    const float* lna_g = (const float*)d_in[17];
    const float* lna_b = (const float*)d_in[18];
    const float* W1    = (const float*)d_in[19];
    const float* b1    = (const float*)d_in[20];
    const float* W2    = (const float*)d_in[21];
    const float* b2    = (const float*)d_in[22];
    const float* gamma = (const float*)d_in[23];
    const float* conv_w= (const float*)d_in[24];
    const float* conv_b= (const float*)d_in[25];
    float* out = (float*)d_out;

    // ---- workspace layout (bytes) ----
    char* base = (char*)d_ws;
    const size_t WT_SQ = (size_t)E_*E_*2;            // 2 MiB each
    const size_t WT_ALL = 5*WT_SQ + 2*(size_t)E_*MLP_*2;
    const size_t BUF = (size_t)M_*E_*2;              // 32 MiB bf16 buffer
    u16* Wqt  = (u16*)base;
    u16* Wkt  = (u16*)(base + 1*WT_SQ);
    u16* Wvt  = (u16*)(base + 2*WT_SQ);
    u16* Wqpt = (u16*)(base + 3*WT_SQ);
    u16* Wkpt = (u16*)(base + 4*WT_SQ);
    u16* W1t  = (u16*)(base + 5*WT_SQ);                       // [4096,1024]
    u16* W2t  = (u16*)(base + 5*WT_SQ + (size_t)E_*MLP_*2);   // [1024,4096]
    char* bufs = base + WT_ALL;
    u16* xb = (u16*)(bufs);            // x bf16 / phiKs / aln_b
    u16* Qb = (u16*)(bufs + 1*BUF);    // Q / attn2_b / h1
    u16* Kb = (u16*)(bufs + 2*BUF);    // K / attn_b / aln_f(lo half)
    u16* Vb = (u16*)(bufs + 3*BUF);    // V / phiQ / aln_f(hi half)
    char* small = bufs + 4*BUF;
    float* qg     = (float*)small;                      // B*E
    float* alpha  = qg + B_*E_;                         // B*H*LK
    float* KV     = alpha + (size_t)B_*H_*LK_;          // B*H*D*D
    float* Ksum   = KV + (size_t)B_*H_*D_*D_;           // B*H*D
    float* scores = Ksum + (size_t)B_*H_*D_;            // B*H*L
    const size_t need = WT_ALL + 4*BUF +
        ((size_t)B_*E_ + (size_t)B_*H_*LK_ + (size_t)B_*H_*D_*D_ + (size_t)B_*H_*D_
         + (size_t)B_*H_*L_)*4;
    if (ws_size < need) return;    // fail visibly rather than fault

    u16* phiKs = xb;                 // after QKV GEMMs, xb is dead
    u16* phiQ  = Vb;                 // after kv_partial, Vb is dead
    u16* attn_b  = Kb;               // after scores+phiK gemm, Kb dead
    u16* attn2_b = Qb;               // after phiQ gemm, Qb dead
    float* aln_f = (float*)Kb;       // 64 MiB spanning Kb+Vb
    u16* aln_b   = xb;
    u16* h1      = Qb;

    dim3 blk256(256);
    // weight conversions (transpose to [N,K] bf16)
    wcvt<<<dim3(32,32),  blk256, 0, stream>>>(Wq, Wqt, E_, E_);
    wcvt<<<dim3(32,32),  blk256, 0, stream>>>(Wk, Wkt, E_, E_);
    wcvt<<<dim3(32,32),  blk256, 0, stream>>>(Wv, Wvt, E_, E_);
    wcvt<<<dim3(32,32),  blk256, 0, stream>>>(Wphi_q, Wqpt, E_, E_);
    wcvt<<<dim3(32,32),  blk256, 0, stream>>>(Wphi_k, Wkpt, E_, E_);
    wcvt<<<dim3(128,32), blk256, 0, stream>>>(W1, W1t, E_, MLP_);
    wcvt<<<dim3(32,128), blk256, 0, stream>>>(W2, W2t, MLP_, E_);
    xcvt<<<M_*E_/1024, blk256, 0, stream>>>(x, xb);
    // QKV projections (bf16 out) + LN in place
    hipLaunchKernelGGL((gemm_bf16<0>), dim3(8,128), blk256, 0, stream, xb, Wqt, bq, Qb, M_, E_, E_, nullptr, nullptr);
    hipLaunchKernelGGL((gemm_bf16<0>), dim3(8,128), blk256, 0, stream, xb, Wkt, bk, Kb, M_, E_, E_, nullptr, nullptr);
    hipLaunchKernelGGL((gemm_bf16<0>), dim3(8,128), blk256, 0, stream, xb, Wvt, bv, Vb, M_, E_, E_, nullptr, nullptr);
    ln_bf16<<<M_, 256, 0, stream>>>(Qb, lnq_g, lnq_b);
    ln_bf16<<<M_, 256, 0, stream>>>(Kb, lnk_g, lnk_b);
    ln_bf16<<<M_, 256, 0, stream>>>(Vb, lnv_g, lnv_b);
    // qg and alpha (parallelized scores + small softmax)
    hipMemsetAsync(qg, 0, B_*E_*sizeof(float), stream);
    qg_partial<<<B_*64, 1024, 0, stream>>>(Qb, qg);
    rala_scores<<<M_/64, 256, 0, stream>>>(Kb, qg, scores);
    rala_softmax<<<B_*H_, 256, 0, stream>>>(scores, alpha);
    // phiK (alpha folded) -> phiKs (= xb region)
    hipLaunchKernelGGL((gemm_bf16<2>), dim3(8,128), blk256, 0, stream, Kb, Wkpt, bphi_k, phiKs, M_, E_, E_, alpha, nullptr);
    // KV / Ksum
    hipMemsetAsync(KV,   0, (size_t)B_*H_*D_*D_*sizeof(float), stream);
    hipMemsetAsync(Ksum, 0, (size_t)B_*H_*D_*sizeof(float), stream);
    kv_partial<<<B_*H_*NS_, 256, 0, stream>>>(phiKs, Vb, KV, Ksum);
    ksum_zero<<<B_*H_, 64, 0, stream>>>(bphi_k, alpha, Ksum);
    // phiQ (= Vb region, V dead after kv_partial)
    hipLaunchKernelGGL((gemm_bf16<1>), dim3(8,128), blk256, 0, stream, Qb, Wqpt, bphi_q, phiQ, M_, E_, E_, nullptr, nullptr);
    // attention output -> attn_b (= Kb region)
    attn_core<<<(M_/64)*H_, 256, 0, stream>>>(phiQ, KV, Ksum, attn_b);
    // conv + gated residual -> attn2_b (= Qb region)
    conv_residual<<<B_*H_*64, 256, 0, stream>>>(attn_b, conv_w, conv_b, gamma, attn2_b);
    // final LN: f32 copy (Kb+Vb) + bf16 copy (xb)
    ln_dual<<<M_, 256, 0, stream>>>(attn2_b, lna_g, lna_b, aln_f, aln_b);
    // MLP + residuals, 4 chunks of 4096 rows; hidden h1 in Qb region
    for (int c=0; c<4; ++c){
        const u16* Ain   = aln_b + (size_t)c*4096*E_;
        const float* Rf  = aln_f + (size_t)c*4096*E_;
        const float* xin = x     + (size_t)c*4096*E_;
        float* outc = out + (size_t)c*4096*E_;
        hipLaunchKernelGGL((gemm_bf16<3>), dim3(32,32), blk256, 0, stream, Ain, W1t, b1, h1, 4096, MLP_, E_, nullptr, nullptr);
        hipLaunchKernelGGL((gemm_bf16<4>), dim3(8,32),  blk256, 0, stream, h1, W2t, b2, outc, 4096, E_, MLP_, Rf, xin);
    }
}

// Round 14
// 1455.522 us; speedup vs baseline: 1.1280x; 1.1280x over previous
//
#include <hip/hip_runtime.h>
#include <hip/hip_bf16.h>

#define B_ 4
#define L_ 4096
#define E_ 1024
#define H_ 16
#define D_ 64
#define MLP_ 4096
#define M_ (B_*L_)
#define LK_ (L_+1)

typedef short bf16x8 __attribute__((ext_vector_type(8)));
typedef float f32x4 __attribute__((ext_vector_type(4)));
typedef unsigned short u16;

__device__ __forceinline__ u16 f2bf(float f){
    union { float f; unsigned u; } x; x.f = f;
    unsigned r = x.u + 0x7FFFu + ((x.u >> 16) & 1u);
    return (u16)(r >> 16);
}
__device__ __forceinline__ float bf2f(u16 u){
    union { unsigned u; float f; } x; x.u = ((unsigned)u) << 16;
    return x.f;
}

__device__ __forceinline__ void gload16(const u16* g, const u16* l){
    __builtin_amdgcn_global_load_lds(
        (const __attribute__((address_space(1))) void*)g,
        (__attribute__((address_space(3))) void*)l, 16, 0, 0);
}

#define BAR() asm volatile("s_barrier" ::: "memory")
#define LGKM0() do{ asm volatile("s_waitcnt lgkmcnt(0)" ::: "memory"); \
                    __builtin_amdgcn_sched_barrier(0); }while(0)

// ---------------- weight convert+transpose: in f32 [K,N] -> out bf16 [N,K] ----------------
__global__ __launch_bounds__(256)
void wcvt(const float* __restrict__ in, u16* __restrict__ out, int K, int N)
{
    __shared__ float t[32][33];
    int tid = threadIdx.x;
    int tx = tid & 31, ty = tid >> 5;
    int bk = blockIdx.y, bn = blockIdx.x;
    #pragma unroll
    for (int i=0;i<4;++i)
        t[ty+8*i][tx] = in[(size_t)(bk*32 + ty + 8*i)*N + bn*32 + tx];
    __syncthreads();
    #pragma unroll
    for (int i=0;i<4;++i)
        out[(size_t)(bn*32 + ty + 8*i)*K + bk*32 + tx] = f2bf(t[tx][ty+8*i]);
}

// ---------------- x convert f32 -> bf16 ----------------
__global__ __launch_bounds__(256)
void xcvt(const float* __restrict__ in, u16* __restrict__ out)
{
    size_t i = ((size_t)blockIdx.x*256 + threadIdx.x)*4;
    float4 v = *(const float4*)(in + i);
    ushort4 o; o.x=f2bf(v.x); o.y=f2bf(v.y); o.z=f2bf(v.z); o.w=f2bf(v.w);
    *(ushort4*)(out + i) = o;
}

// ================= 256x256 8-phase bf16 MFMA GEMM (T3+T4+T5) =================
// C = A[M,K] @ Wt[N,K]^T + bias. 512 threads = 8 waves (2M x 4N), BK=64,
// double-buffered LDS, counted vmcnt, raw barriers, setprio around MFMA.
// EPI 0: bf16; 1: tanh+1 bf16; 2: (tanh+1)*alpha bf16; 3: gelu bf16
#define PH_CORE(BI,Q) \
    x00=rdA(BI,2*Q+0,0); x01=rdA(BI,2*Q+0,1); x10=rdA(BI,2*Q+1,0); x11=rdA(BI,2*Q+1,1);
#define READB(BI) do{ \
    _Pragma("unroll") for(int nj_=0;nj_<4;++nj_){ \
      _Pragma("unroll") for(int kq_=0;kq_<2;++kq_) Bf[nj_][kq_]=rdB(BI,nj_,kq_); } }while(0)
#define PH_MFMA(Q) \
  __builtin_amdgcn_s_setprio(1); \
  acc[2*Q+0][0]=__builtin_amdgcn_mfma_f32_16x16x32_bf16(x00,Bf[0][0],acc[2*Q+0][0],0,0,0); \
  acc[2*Q+0][0]=__builtin_amdgcn_mfma_f32_16x16x32_bf16(x01,Bf[0][1],acc[2*Q+0][0],0,0,0); \
  acc[2*Q+0][1]=__builtin_amdgcn_mfma_f32_16x16x32_bf16(x00,Bf[1][0],acc[2*Q+0][1],0,0,0); \
  acc[2*Q+0][1]=__builtin_amdgcn_mfma_f32_16x16x32_bf16(x01,Bf[1][1],acc[2*Q+0][1],0,0,0); \
  acc[2*Q+0][2]=__builtin_amdgcn_mfma_f32_16x16x32_bf16(x00,Bf[2][0],acc[2*Q+0][2],0,0,0); \
  acc[2*Q+0][2]=__builtin_amdgcn_mfma_f32_16x16x32_bf16(x01,Bf[2][1],acc[2*Q+0][2],0,0,0); \
  acc[2*Q+0][3]=__builtin_amdgcn_mfma_f32_16x16x32_bf16(x00,Bf[3][0],acc[2*Q+0][3],0,0,0); \
  acc[2*Q+0][3]=__builtin_amdgcn_mfma_f32_16x16x32_bf16(x01,Bf[3][1],acc[2*Q+0][3],0,0,0); \
  acc[2*Q+1][0]=__builtin_amdgcn_mfma_f32_16x16x32_bf16(x10,Bf[0][0],acc[2*Q+1][0],0,0,0); \
  acc[2*Q+1][0]=__builtin_amdgcn_mfma_f32_16x16x32_bf16(x11,Bf[0][1],acc[2*Q+1][0],0,0,0); \
  acc[2*Q+1][1]=__builtin_amdgcn_mfma_f32_16x16x32_bf16(x10,Bf[1][0],acc[2*Q+1][1],0,0,0); \
  acc[2*Q+1][1]=__builtin_amdgcn_mfma_f32_16x16x32_bf16(x11,Bf[1][1],acc[2*Q+1][1],0,0,0); \
  acc[2*Q+1][2]=__builtin_amdgcn_mfma_f32_16x16x32_bf16(x10,Bf[2][0],acc[2*Q+1][2],0,0,0); \
  acc[2*Q+1][2]=__builtin_amdgcn_mfma_f32_16x16x32_bf16(x11,Bf[2][1],acc[2*Q+1][2],0,0,0); \
  acc[2*Q+1][3]=__builtin_amdgcn_mfma_f32_16x16x32_bf16(x10,Bf[3][0],acc[2*Q+1][3],0,0,0); \
  acc[2*Q+1][3]=__builtin_amdgcn_mfma_f32_16x16x32_bf16(x11,Bf[3][1],acc[2*Q+1][3],0,0,0); \
  __builtin_amdgcn_s_setprio(0);

template<int EPI>
__global__ __launch_bounds__(512, 1)
void gemm256(const u16* __restrict__ A, const u16* __restrict__ Wt,
             const float* __restrict__ bias, u16* __restrict__ Cout,
             int M, int N, int K, const float* __restrict__ P1)
{
    __shared__ __align__(16) u16 As[2][256*64];
    __shared__ __align__(16) u16 Bs[2][256*64];
    const int tid = threadIdx.x;
    const int lane = tid & 63, w = tid >> 6;
    const int wr = w >> 2, wc = w & 3;
    const int row16 = lane & 15, kb = lane >> 4;
    const int bm = blockIdx.y, bn = blockIdx.x;
    const u16* Ab = A  + (size_t)bm*256*K;
    const u16* Bb = Wt + (size_t)bn*256*K;
    const int NITER = K >> 7;                   // K/128, even tiles handled pairwise
    const int srow = lane >> 3;
    const int scol = (lane & 7) * 8;

    auto stageA = [&](int bi, int h, int t){
        #pragma unroll
        for (int s = 0; s < 2; ++s){
            int r = h*128 + w*16 + s*8;
            gload16(Ab + (size_t)(r + srow)*K + t*64 + scol, &As[bi][r*64]);
        }
    };
    auto stageB = [&](int bi, int h, int t){
        #pragma unroll
        for (int s = 0; s < 2; ++s){
            int r = h*128 + w*16 + s*8;
            gload16(Bb + (size_t)(r + srow)*K + t*64 + scol, &Bs[bi][r*64]);
        }
    };
    auto rdA = [&](int bi, int mi, int kq)->bf16x8{
        int r = wr*128 + mi*16 + row16;
        return *(const bf16x8*)&As[bi][r*64 + kq*32 + kb*8];
    };
    auto rdB = [&](int bi, int nj, int kq)->bf16x8{
        int r = wc*64 + nj*16 + row16;
        return *(const bf16x8*)&Bs[bi][r*64 + kq*32 + kb*8];
    };

    f32x4 acc[8][4] = {};
    bf16x8 Bf[4][2];
    bf16x8 x00, x01, x10, x11;

    // prologue: tile0 -> buf0 (A+B), tile1.B -> buf1 (buf1.A staged JIT in ph1)
    stageA(0,0,0); stageA(0,1,0);
    stageB(0,0,0); stageB(0,1,0);
    stageB(1,0,1); stageB(1,1,1);
    asm volatile("s_waitcnt vmcnt(4)" ::: "memory");
    BAR();

    for (int n = 0; n < NITER; ++n){
        const int t1 = 2*n + 1;
        const bool nl = (n + 1 < NITER);
        // ---- ph1: buf0 {B all + A q0}; stage buf1.A <- t1 (JIT)
        READB(0);
        PH_CORE(0,0);
        stageA(1,0,t1); stageA(1,1,t1);
        BAR(); LGKM0(); PH_MFMA(0); BAR();
        // ---- ph2: A q1; stage buf0.B-h0 <- t1+1
        PH_CORE(0,1);
        if (nl) stageB(0,0,t1+1);
        BAR(); LGKM0(); PH_MFMA(1); BAR();
        // ---- ph3: A q2; stage buf0.B-h1 <- t1+1
        PH_CORE(0,2);
        if (nl) stageB(0,1,t1+1);
        BAR(); LGKM0(); PH_MFMA(2); BAR();
        // ---- ph4: A q3; counted vmcnt (buf1.A must be landed for ph5-8)
        PH_CORE(0,3);
        if (nl) asm volatile("s_waitcnt vmcnt(4)" ::: "memory");
        else    asm volatile("s_waitcnt vmcnt(0)" ::: "memory");
        BAR(); LGKM0(); PH_MFMA(3); BAR();
        // ---- ph5: buf1 {B all + A q0}; stage buf0.A <- t1+1
        READB(1);
        PH_CORE(1,0);
        if (nl){ stageA(0,0,t1+1); stageA(0,1,t1+1); }
        BAR(); LGKM0(); PH_MFMA(0); BAR();
        // ---- ph6: A q1; stage buf1.B-h0 <- t1+2
        PH_CORE(1,1);
        if (nl) stageB(1,0,t1+2);
        BAR(); LGKM0(); PH_MFMA(1); BAR();
        // ---- ph7: A q2; stage buf1.B-h1 <- t1+2
        PH_CORE(1,2);
        if (nl) stageB(1,1,t1+2);
        BAR(); LGKM0(); PH_MFMA(2); BAR();
        // ---- ph8: A q3; counted vmcnt (buf0 must be landed for next ph1-4)
        PH_CORE(1,3);
        if (nl) asm volatile("s_waitcnt vmcnt(4)" ::: "memory");
        BAR(); LGKM0(); PH_MFMA(3); BAR();
    }

    #pragma unroll
    for (int mi = 0; mi < 8; ++mi){
        int rbase = bm*256 + wr*128 + mi*16 + kb*4;
        #pragma unroll
        for (int nj = 0; nj < 4; ++nj){
            int col = bn*256 + wc*64 + nj*16 + row16;
            float bcol = bias[col];
            #pragma unroll
            for (int r = 0; r < 4; ++r){
                int row = rbase + r;
                float v = acc[mi][nj][r] + bcol;
                if (EPI == 1) v = tanhf(v) + 1.0f;
                if (EPI == 2){
                    int b = row >> 12, l = row & 4095, h = col >> 6;
                    v = (tanhf(v) + 1.0f) * P1[(size_t)(b*16 + h)*LK_ + 1 + l];
                }
                if (EPI == 3) v = 0.5f*v*(1.0f + erff(v*0.70710678118654752f));
                Cout[(size_t)row*N + col] = f2bf(v);
            }
        }
    }
}

// ---------------- 128x128 bf16 MFMA GEMM (reg-staged, round-10 form) ----------------
// EPI 4: f32 out = v + P1 + P2  (used for MLP-down)
template<int EPI>
__global__ __launch_bounds__(256)
void gemm_bf16(const u16* __restrict__ A, const u16* __restrict__ Wt,
               const float* __restrict__ bias, void* __restrict__ Cout,
               int M, int N, int K,
               const float* __restrict__ P1, const float* __restrict__ P2)
{
    __shared__ __align__(16) u16 As[128*64];
    __shared__ __align__(16) u16 Bs[128*64];
    const int tid = threadIdx.x;
    const int bm = blockIdx.y, bn = blockIdx.x;
    const int lane = tid & 63, w = tid >> 6;
    const int wr = w >> 1, wc = w & 1;
    const int row16 = lane & 15, kb = lane >> 4;
    f32x4 acc[4][4] = {};

    for (int kt = 0; kt < K; kt += 64) {
        #pragma unroll
        for (int i = 0; i < 4; ++i) {
            int c = tid + 256*i;
            int row = c >> 3, kc = c & 7;
            uint4 va = *(const uint4*)(A  + (size_t)(bm*128 + row)*K + kt + kc*8);
            uint4 vb = *(const uint4*)(Wt + (size_t)(bn*128 + row)*K + kt + kc*8);
            int off = row*128 + ((kc*16) ^ ((row & 7) << 4));
            *(uint4*)((char*)As + off) = va;
            *(uint4*)((char*)Bs + off) = vb;
        }
        __syncthreads();
        #pragma unroll
        for (int kk = 0; kk < 2; ++kk) {
            bf16x8 af[4], bfr[4];
            #pragma unroll
            for (int mi = 0; mi < 4; ++mi) {
                int r = wr*64 + mi*16 + row16;
                int off = r*128 + ((kk*64 + kb*16) ^ ((row16 & 7) << 4));
                af[mi] = *(const bf16x8*)((const char*)As + off);
            }
            #pragma unroll
            for (int nj = 0; nj < 4; ++nj) {
                int r = wc*64 + nj*16 + row16;
                int off = r*128 + ((kk*64 + kb*16) ^ ((row16 & 7) << 4));
                bfr[nj] = *(const bf16x8*)((const char*)Bs + off);
            }
            #pragma unroll
            for (int mi = 0; mi < 4; ++mi)
                #pragma unroll
                for (int nj = 0; nj < 4; ++nj)
                    acc[mi][nj] = __builtin_amdgcn_mfma_f32_16x16x32_bf16(af[mi], bfr[nj], acc[mi][nj], 0, 0, 0);
        }
        __syncthreads();
    }
    #pragma unroll
    for (int nj = 0; nj < 4; ++nj) {
        int col = bn*128 + wc*64 + nj*16 + row16;
        float bcol = bias[col];
        #pragma unroll
        for (int mi = 0; mi < 4; ++mi) {
            int rbase = bm*128 + wr*64 + mi*16 + kb*4;
            #pragma unroll
            for (int r = 0; r < 4; ++r) {
                int row = rbase + r;
                float v = acc[mi][nj][r] + bcol;
                if (EPI == 4) {
                    ((float*)Cout)[(size_t)row*N + col] = v + P1[(size_t)row*N + col] + P2[(size_t)row*N + col];
                } else {
                    ((u16*)Cout)[(size_t)row*N + col] = f2bf(v);
                }
            }
        }
    }
}

// ---------------- row LayerNorm over E=1024 (bf16 in-place) ----------------
__global__ __launch_bounds__(256)
void ln_bf16(u16* __restrict__ x, const float* __restrict__ g, const float* __restrict__ bta)
{
    __shared__ float red[8];
    const int row = blockIdx.x, tid = threadIdx.x;
    u16* p = x + (size_t)row*E_;
    ushort4 raw = *(const ushort4*)(p + tid*4);
    float v[4] = {bf2f(raw.x), bf2f(raw.y), bf2f(raw.z), bf2f(raw.w)};
    float s=0.f, s2=0.f;
    #pragma unroll
    for (int i=0;i<4;++i){ s += v[i]; s2 += v[i]*v[i]; }
    #pragma unroll
    for (int o=32;o;o>>=1){ s += __shfl_xor(s,o); s2 += __shfl_xor(s2,o); }
    int wv = tid >> 6;
    if ((tid & 63) == 0){ red[wv] = s; red[4+wv] = s2; }
    __syncthreads();
    s  = red[0]+red[1]+red[2]+red[3];
    s2 = red[4]+red[5]+red[6]+red[7];
    float mu = s * (1.0f/E_);
    float var = s2 * (1.0f/E_) - mu*mu;
    float rs = rsqrtf(var + 1e-5f);
    ushort4 o4;
    float r0 = (v[0]-mu)*rs*g[tid*4+0] + bta[tid*4+0];
    float r1 = (v[1]-mu)*rs*g[tid*4+1] + bta[tid*4+1];
    float r2 = (v[2]-mu)*rs*g[tid*4+2] + bta[tid*4+2];
    float r3 = (v[3]-mu)*rs*g[tid*4+3] + bta[tid*4+3];
    o4.x=f2bf(r0); o4.y=f2bf(r1); o4.z=f2bf(r2); o4.w=f2bf(r3);
    *(ushort4*)(p + tid*4) = o4;
}

// ---------------- final LN: bf16 in -> f32 out + bf16 out ----------------
__global__ __launch_bounds__(256)
void ln_dual(const u16* __restrict__ x, const float* __restrict__ g, const float* __restrict__ bta,
             float* __restrict__ of, u16* __restrict__ ob)
{
    __shared__ float red[8];
    const int row = blockIdx.x, tid = threadIdx.x;
    const u16* p = x + (size_t)row*E_;
    ushort4 raw = *(const ushort4*)(p + tid*4);
    float v[4] = {bf2f(raw.x), bf2f(raw.y), bf2f(raw.z), bf2f(raw.w)};
    float s=0.f, s2=0.f;
    #pragma unroll
    for (int i=0;i<4;++i){ s += v[i]; s2 += v[i]*v[i]; }
    #pragma unroll
    for (int o=32;o;o>>=1){ s += __shfl_xor(s,o); s2 += __shfl_xor(s2,o); }
    int wv = tid >> 6;
    if ((tid & 63) == 0){ red[wv] = s; red[4+wv] = s2; }
    __syncthreads();
    s  = red[0]+red[1]+red[2]+red[3];
    s2 = red[4]+red[5]+red[6]+red[7];
    float mu = s * (1.0f/E_);
    float var = s2 * (1.0f/E_) - mu*mu;
    float rs = rsqrtf(var + 1e-5f);
    float4 rf; ushort4 o4;
    rf.x = (v[0]-mu)*rs*g[tid*4+0] + bta[tid*4+0];
    rf.y = (v[1]-mu)*rs*g[tid*4+1] + bta[tid*4+1];
    rf.z = (v[2]-mu)*rs*g[tid*4+2] + bta[tid*4+2];
    rf.w = (v[3]-mu)*rs*g[tid*4+3] + bta[tid*4+3];
    o4.x=f2bf(rf.x); o4.y=f2bf(rf.y); o4.z=f2bf(rf.z); o4.w=f2bf(rf.w);
    *(float4*)(of + (size_t)row*E_ + tid*4) = rf;
    *(ushort4*)(ob + (size_t)row*E_ + tid*4) = o4;
}

// ---------------- qg partial sums (bf16 Q) ----------------
__global__ __launch_bounds__(1024)
void qg_partial(const u16* __restrict__ Q, float* __restrict__ qg)
{
    int b = blockIdx.x >> 6;
    int c = blockIdx.x & 63;
    int e = threadIdx.x;
    float s = 0.f;
    const u16* p = Q + ((size_t)b*L_ + c*64)*E_ + e;
    for (int l=0; l<64; ++l) s += bf2f(p[(size_t)l*E_]);
    atomicAdd(&qg[b*E_ + e], s);
}

// ---------------- RALA scores ----------------
__global__ __launch_bounds__(256)
void rala_scores(const u16* __restrict__ K, const float* __restrict__ qg,
                 float* __restrict__ scores)
{
    int blk = blockIdx.x;
    int row0 = blk * 64;
    int b = row0 >> 12;
    int tid = threadIdx.x;
    int lane = tid & 63, w = tid >> 6;
    float qr[16];
    const float qscale = 1.0f/(L_ * 8.0f);
    #pragma unroll
    for (int j=0;j<16;++j) qr[j] = qg[b*E_ + lane*16 + j] * qscale;
    for (int it = 0; it < 16; ++it) {
        int r = row0 + w*16 + it;
        const u16* p = K + (size_t)r*E_ + lane*16;
        uint4 a0 = *(const uint4*)(p);
        uint4 a1 = *(const uint4*)(p + 8);
        const u16* u0 = (const u16*)&a0;
        const u16* u1 = (const u16*)&a1;
        float s = 0.f;
        #pragma unroll
        for (int j=0;j<8;++j) s = fmaf(bf2f(u0[j]), qr[j], s);
        #pragma unroll
        for (int j=0;j<8;++j) s = fmaf(bf2f(u1[j]), qr[8+j], s);
        s += __shfl_xor(s, 1);
        s += __shfl_xor(s, 2);
        if ((lane & 3) == 0) {
            int h = lane >> 2;
            int l = r & (L_-1);
            scores[((size_t)(b*H_ + h))*L_ + l] = s;
        }
    }
}

// ---------------- softmax over L+1 (zero token at 0) -> alpha ----------------
__global__ __launch_bounds__(256)
void rala_softmax(const float* __restrict__ scores, float* __restrict__ alpha)
{
    __shared__ float red[8];
    int bh = blockIdx.x, tid = threadIdx.x;
    const float* sc = scores + (size_t)bh*L_;
    float v[16];
    float mx = 0.f;
    #pragma unroll
    for (int i=0;i<16;++i){ v[i] = sc[tid + i*256]; mx = fmaxf(mx, v[i]); }
    #pragma unroll
    for (int o=32;o;o>>=1) mx = fmaxf(mx, __shfl_xor(mx,o));
    int wv = tid >> 6;
    if ((tid & 63) == 0) red[wv] = mx;
    __syncthreads();
    mx = fmaxf(fmaxf(red[0],red[1]), fmaxf(red[2],red[3]));
    float sum = 0.f;
    #pragma unroll
    for (int i=0;i<16;++i){ v[i] = expf(v[i]-mx); sum += v[i]; }
    #pragma unroll
    for (int o=32;o;o>>=1) sum += __shfl_xor(sum,o);
    __syncthreads();
    if ((tid & 63) == 0) red[4+wv] = sum;
    __syncthreads();
    float Z = red[4]+red[5]+red[6]+red[7] + expf(-mx);
    float scale = (float)L_ / Z;
    float* al = alpha + (size_t)bh*LK_;
    #pragma unroll
    for (int i=0;i<16;++i) al[1 + tid + i*256] = v[i]*scale;
    if (tid==0) al[0] = expf(-mx)*scale;
}

// ---------------- KV & Ksum ----------------
#define NS_ 8
__global__ __launch_bounds__(256)
void kv_partial(const u16* __restrict__ phiKs, const u16* __restrict__ Vb,
                float* __restrict__ KV, float* __restrict__ Ksum)
{
    __shared__ float Ps[64][65];
    __shared__ float Vs[64][65];
    int blk = blockIdx.x;
    int s = blk & (NS_-1);
    int h = (blk >> 3) & 15;
    int b = blk >> 7;
    int tid = threadIdx.x;
    int tx = tid & 15, ty = tid >> 4;
    const size_t bh = (size_t)(b*H_ + h);
    float acc[4][4] = {};
    float ksl = 0.f;
    for (int ch = 0; ch < 8; ++ch) {
        int lbase = s*512 + ch*64;
        #pragma unroll
        for (int i=0;i<16;++i){
            int idx = tid + i*256;
            int r = idx >> 6, c2 = idx & 63;
            size_t g = ((size_t)b*L_ + lbase + r)*E_ + h*64 + c2;
            Ps[r][c2] = bf2f(phiKs[g]);
            Vs[r][c2] = bf2f(Vb[g]);
        }
        __syncthreads();
        #pragma unroll 8
        for (int l=0; l<64; ++l){
            float p[4], vv[4];
            #pragma unroll
            for (int i=0;i<4;++i) p[i] = Ps[l][ty*4+i];
            #pragma unroll
            for (int j=0;j<4;++j) vv[j] = Vs[l][tx*4+j];
            #pragma unroll
            for (int i=0;i<4;++i)
                #pragma unroll
                for (int j=0;j<4;++j)
                    acc[i][j] = fmaf(p[i], vv[j], acc[i][j]);
        }
        if (tid < 64){
            float t = 0.f;
            #pragma unroll 8
            for (int l=0; l<64; ++l) t += Ps[l][tid];
            ksl += t;
        }
        __syncthreads();
    }
    #pragma unroll
    for (int i=0;i<4;++i)
        #pragma unroll
        for (int j=0;j<4;++j)
            atomicAdd(&KV[(bh*D_ + ty*4+i)*D_ + tx*4+j], acc[i][j]);
    if (tid < 64) atomicAdd(&Ksum[bh*D_ + tid], ksl);
}

// zero-token: Ksum += (tanh(bphi_k)+1) * alpha0
__global__ void ksum_zero(const float* __restrict__ bphi_k,
                          const float* __restrict__ alpha, float* __restrict__ Ksum)
{
    int bh = blockIdx.x; int h = bh & 15; int d = threadIdx.x;
    float a0 = alpha[(size_t)bh*LK_];
    Ksum[(size_t)bh*D_ + d] += (tanhf(bphi_k[h*D_ + d]) + 1.0f) * a0;
}

// ---------------- attn core ----------------
__global__ __launch_bounds__(256)
void attn_core(const u16* __restrict__ phiQ, const float* __restrict__ KV,
               const float* __restrict__ Ksum, u16* __restrict__ attn)
{
    __shared__ float KVs[64][65];
    __shared__ float Ps[64][65];
    __shared__ float Ks_[64];
    int gid = blockIdx.x;
    int h = gid & 15; int rchunk = gid >> 4;
    int row0 = rchunk * 64;
    int b = row0 >> 12;
    const size_t bh = (size_t)(b*H_ + h);
    int tid = threadIdx.x;
    int tx = tid & 15, ty = tid >> 4;
    #pragma unroll
    for (int i=0;i<16;++i){
        int idx = tid + i*256;
        int r = idx >> 6, c2 = idx & 63;
        KVs[r][c2] = KV[bh*D_*D_ + r*64 + c2];
        Ps[r][c2]  = bf2f(phiQ[((size_t)row0 + r)*E_ + h*64 + c2]);
    }
    if (tid < 64) Ks_[tid] = Ksum[bh*D_ + tid];
    __syncthreads();
    float num[4][4] = {};
    float den[4] = {};
    for (int d=0; d<64; ++d){
        float kd = Ks_[d];
        float4 kv4 = *(const float4*)&KVs[d][tx*4];
        float kvv[4] = {kv4.x, kv4.y, kv4.z, kv4.w};
        #pragma unroll
        for (int i=0;i<4;++i){
            float q = Ps[ty*4+i][d];
            den[i] = fmaf(q, kd, den[i]);
            #pragma unroll
            for (int j=0;j<4;++j)
                num[i][j] = fmaf(q, kvv[j], num[i][j]);
        }
    }
    #pragma unroll
    for (int i=0;i<4;++i){
        float r = 1.0f / (den[i] + 1e-6f);
        #pragma unroll
        for (int j=0;j<4;++j)
            attn[((size_t)row0 + ty*4 + i)*E_ + h*64 + tx*4 + j] = f2bf(num[i][j] * r);
    }
}

// ---------------- grouped conv + gated residual ----------------
__global__ __launch_bounds__(256)
void conv_residual(const u16* __restrict__ attn, const float* __restrict__ conv_w,
                   const float* __restrict__ conv_b, const float* __restrict__ gamma_p,
                   u16* __restrict__ out)
{
    __shared__ float As_[68][65];
    int blk = blockIdx.x;
    int lc = blk & 63; int h = (blk>>6) & 15; int b = blk >> 10;
    int tid = threadIdx.x;
    int e = tid & 63;
    int lg = tid >> 6;
    for (int i=tid; i<68*64; i+=256){
        int r = i>>6, cc = i&63;
        int l = lc*64 - 2 + r;
        As_[r][cc] = (l>=0 && l<L_) ? bf2f(attn[((size_t)b*L_+l)*E_ + h*D_ + cc]) : 0.f;
    }
    __syncthreads();
    float acc[16] = {};
    const float* wbase = conv_w + ((size_t)(h*D_ + e))*320;
    for (int d=0; d<64; ++d){
        float w0 = wbase[d*5+0], w1 = wbase[d*5+1], w2 = wbase[d*5+2],
              w3 = wbase[d*5+3], w4 = wbase[d*5+4];
        float a[20];
        #pragma unroll
        for (int r=0;r<20;++r) a[r] = As_[lg*16 + r][d];
        #pragma unroll
        for (int i=0;i<16;++i)
            acc[i] = fmaf(a[i+4],w4, fmaf(a[i+3],w3, fmaf(a[i+2],w2,
                     fmaf(a[i+1],w1, fmaf(a[i+0],w0, acc[i])))));
    }
    float gamma = *gamma_p;
    float bc = conv_b[h*D_ + e];
    #pragma unroll
    for (int i=0;i<16;++i){
        int l = lc*64 + lg*16 + i;
        float v = As_[lg*16 + i + 2][e] + gamma*(acc[i] + bc);
        out[((size_t)b*L_+l)*E_ + h*D_ + e] = f2bf(v);
    }
}

extern "C" void kernel_launch(void* const* d_in, const int* in_sizes, int n_in,
                              void* d_out, int out_size, void* d_ws, size_t ws_size,
                              hipStream_t stream)
{
    const float* x     = (const float*)d_in[0];
    const float* Wq    = (const float*)d_in[1];
    const float* bq    = (const float*)d_in[2];
    const float* lnq_g = (const float*)d_in[3];
    const float* lnq_b = (const float*)d_in[4];
    const float* Wk    = (const float*)d_in[5];
    const float* bk    = (const float*)d_in[6];
    const float* lnk_g = (const float*)d_in[7];
    const float* lnk_b = (const float*)d_in[8];
    const float* Wv    = (const float*)d_in[9];
    const float* bv    = (const float*)d_in[10];
    const float* lnv_g = (const float*)d_in[11];
    const float* lnv_b = (const float*)d_in[12];
    const float* Wphi_q= (const float*)d_in[13];
    const float* bphi_q= (const float*)d_in[14];
    const float* Wphi_k= (const float*)d_in[15];
    const float* bphi_k= (const float*)d_in[16];
    const float* lna_g = (const float*)d_in[17];
    const float* lna_b = (const float*)d_in[18];
    const float* W1    = (const float*)d_in[19];
    const float* b1    = (const float*)d_in[20];
    const float* W2    = (const float*)d_in[21];
    const float* b2    = (const float*)d_in[22];
    const float* gamma = (const float*)d_in[23];
    const float* conv_w= (const float*)d_in[24];
    const float* conv_b= (const float*)d_in[25];
    float* out = (float*)d_out;

    char* base = (char*)d_ws;
    const size_t WT_SQ = (size_t)E_*E_*2;
    const size_t WT_ALL = 5*WT_SQ + 2*(size_t)E_*MLP_*2;
    const size_t BUF = (size_t)M_*E_*2;
    u16* Wqt  = (u16*)base;
    u16* Wkt  = (u16*)(base + 1*WT_SQ);
    u16* Wvt  = (u16*)(base + 2*WT_SQ);
    u16* Wqpt = (u16*)(base + 3*WT_SQ);
    u16* Wkpt = (u16*)(base + 4*WT_SQ);
    u16* W1t  = (u16*)(base + 5*WT_SQ);
    u16* W2t  = (u16*)(base + 5*WT_SQ + (size_t)E_*MLP_*2);
    char* bufs = base + WT_ALL;
    u16* xb = (u16*)(bufs);
    u16* Qb = (u16*)(bufs + 1*BUF);
    u16* Kb = (u16*)(bufs + 2*BUF);
    u16* Vb = (u16*)(bufs + 3*BUF);
    char* small = bufs + 4*BUF;
    float* qg     = (float*)small;
    float* alpha  = qg + B_*E_;
    float* KV     = alpha + (size_t)B_*H_*LK_;
    float* Ksum   = KV + (size_t)B_*H_*D_*D_;
    float* scores = Ksum + (size_t)B_*H_*D_;
    const size_t need = WT_ALL + 4*BUF +
        ((size_t)B_*E_ + (size_t)B_*H_*LK_ + (size_t)B_*H_*D_*D_ + (size_t)B_*H_*D_
         + (size_t)B_*H_*L_)*4;
    if (ws_size < need) return;

    u16* phiKs = xb;
    u16* phiQ  = Vb;
    u16* attn_b  = Kb;
    u16* attn2_b = Qb;
    float* aln_f = (float*)Kb;
    u16* aln_b   = xb;
    u16* h1      = Qb;

    dim3 blk256(256), blk512(512);
    wcvt<<<dim3(32,32),  blk256, 0, stream>>>(Wq, Wqt, E_, E_);
    wcvt<<<dim3(32,32),  blk256, 0, stream>>>(Wk, Wkt, E_, E_);
    wcvt<<<dim3(32,32),  blk256, 0, stream>>>(Wv, Wvt, E_, E_);
    wcvt<<<dim3(32,32),  blk256, 0, stream>>>(Wphi_q, Wqpt, E_, E_);
    wcvt<<<dim3(32,32),  blk256, 0, stream>>>(Wphi_k, Wkpt, E_, E_);
    wcvt<<<dim3(128,32), blk256, 0, stream>>>(W1, W1t, E_, MLP_);
    wcvt<<<dim3(32,128), blk256, 0, stream>>>(W2, W2t, MLP_, E_);
    xcvt<<<M_*E_/1024, blk256, 0, stream>>>(x, xb);
    // QKV projections (256^2 8-phase) + LN in place
    hipLaunchKernelGGL((gemm256<0>), dim3(4,64), blk512, 0, stream, xb, Wqt, bq, Qb, M_, E_, E_, nullptr);
    hipLaunchKernelGGL((gemm256<0>), dim3(4,64), blk512, 0, stream, xb, Wkt, bk, Kb, M_, E_, E_, nullptr);
    hipLaunchKernelGGL((gemm256<0>), dim3(4,64), blk512, 0, stream, xb, Wvt, bv, Vb, M_, E_, E_, nullptr);
    ln_bf16<<<M_, 256, 0, stream>>>(Qb, lnq_g, lnq_b);
    ln_bf16<<<M_, 256, 0, stream>>>(Kb, lnk_g, lnk_b);
    ln_bf16<<<M_, 256, 0, stream>>>(Vb, lnv_g, lnv_b);
    // qg and alpha
    hipMemsetAsync(qg, 0, B_*E_*sizeof(float), stream);
    qg_partial<<<B_*64, 1024, 0, stream>>>(Qb, qg);
    rala_scores<<<M_/64, 256, 0, stream>>>(Kb, qg, scores);
    rala_softmax<<<B_*H_, 256, 0, stream>>>(scores, alpha);
    // phiK (alpha folded)
    hipLaunchKernelGGL((gemm256<2>), dim3(4,64), blk512, 0, stream, Kb, Wkpt, bphi_k, phiKs, M_, E_, E_, alpha);
    // KV / Ksum
    hipMemsetAsync(KV,   0, (size_t)B_*H_*D_*D_*sizeof(float), stream);
    hipMemsetAsync(Ksum, 0, (size_t)B_*H_*D_*sizeof(float), stream);
    kv_partial<<<B_*H_*NS_, 256, 0, stream>>>(phiKs, Vb, KV, Ksum);
    ksum_zero<<<B_*H_, 64, 0, stream>>>(bphi_k, alpha, Ksum);
    // phiQ
    hipLaunchKernelGGL((gemm256<1>), dim3(4,64), blk512, 0, stream, Qb, Wqpt, bphi_q, phiQ, M_, E_, E_, nullptr);
    // attention output -> attn_b
    attn_core<<<(M_/64)*H_, 256, 0, stream>>>(phiQ, KV, Ksum, attn_b);
    // conv + gated residual -> attn2_b
    conv_residual<<<B_*H_*64, 256, 0, stream>>>(attn_b, conv_w, conv_b, gamma, attn2_b);
    // final LN
    ln_dual<<<M_, 256, 0, stream>>>(attn2_b, lna_g, lna_b, aln_f, aln_b);
    // MLP + residuals, 4 chunks; up = 256^2 8-phase, down = 128^2 (f32 epilogue)
    for (int c=0; c<4; ++c){
        const u16* Ain   = aln_b + (size_t)c*4096*E_;
        const float* Rf  = aln_f + (size_t)c*4096*E_;
        const float* xin = x     + (size_t)c*4096*E_;
        float* outc = out + (size_t)c*4096*E_;
        hipLaunchKernelGGL((gemm256<3>), dim3(16,16), blk512, 0, stream, Ain, W1t, b1, h1, 4096, MLP_, E_, nullptr);
        hipLaunchKernelGGL((gemm_bf16<4>), dim3(8,32), blk256, 0, stream, h1, W2t, b2, outc, 4096, E_, MLP_, Rf, xin);
    }
}